// Round 14
// baseline (172.473 us; speedup 1.0000x reference)
//
#include <hip/hip_runtime.h>
#include <hip/hip_bf16.h>

#define B_SZ   128
#define T_SZ   2048
#define ENCH   512
#define ATTN_  128
#define NBLK   256               // persistent, 1 block/CU
#define SEGS_PER_BLK 4           // 4 x (16 waves x 16 rows) = 1024 rows/block

typedef __attribute__((ext_vector_type(8))) short short8;
typedef __attribute__((ext_vector_type(4))) float f32x4;

__device__ __forceinline__ unsigned short f2bf_rne(float f) {
  unsigned u = __builtin_bit_cast(unsigned, f);
  u += 0x7FFFu + ((u >> 16) & 1u);
  return (unsigned short)(u >> 16);
}
__device__ __forceinline__ float fast_tanh(float x) {
  float e = __expf(2.f * x);
  return 1.f - __fdividef(2.f, e + 1.f);
}
__device__ __forceinline__ short8 pack8(float4 a, float4 b) {
  union { unsigned u[4]; short8 s; } r;
  asm("v_cvt_pk_bf16_f32 %0, %1, %2" : "=v"(r.u[0]) : "v"(a.x), "v"(a.y));
  asm("v_cvt_pk_bf16_f32 %0, %1, %2" : "=v"(r.u[1]) : "v"(a.z), "v"(a.w));
  asm("v_cvt_pk_bf16_f32 %0, %1, %2" : "=v"(r.u[2]) : "v"(b.x), "v"(b.y));
  asm("v_cvt_pk_bf16_f32 %0, %1, %2" : "=v"(r.u[3]) : "v"(b.z), "v"(b.w));
  return r.s;
}
template<int CTRL>
__device__ __forceinline__ float dpp_add(float v) {
  int t = __builtin_amdgcn_update_dpp(0, __builtin_bit_cast(int, v),
                                      CTRL, 0xf, 0xf, true);
  return v + __builtin_bit_cast(float, t);
}
__device__ __forceinline__ float sum16(float v) {
  v = dpp_add<0xB1>(v);    // quad_perm xor1
  v = dpp_add<0x4E>(v);    // quad_perm xor2
  v = dpp_add<0x141>(v);   // row_half_mirror
  v = dpp_add<0x140>(v);   // row_mirror
  return v;
}
// bf16 element (packed in short8) -> f32
__device__ __forceinline__ float bfel(short8 v, int j_half, bool hi) {
  unsigned u = __builtin_bit_cast(unsigned, (int)((((int*)&v))[j_half]));
  return __builtin_bit_cast(float, hi ? (u & 0xFFFF0000u) : (u << 16));
}

// ---- K0 (fused prep): blocks 0-31 convert W_enc fp32->bf16 frag-linear;
//      blocks 32-159 compute dec_proj[b] = W_dec . dec[b]. ----
__global__ void k_prep(const float* __restrict__ w,
                       unsigned short* __restrict__ o,
                       const float* __restrict__ dec,
                       const float* __restrict__ wdec,
                       float* __restrict__ dout) {
  if (blockIdx.x < 32) {
    int idx = blockIdx.x * 256 + threadIdx.x;   // 8192 threads
    int l   = idx & 63;
    int wks = idx >> 6;
    int cg  = wks >> 4, ks = wks & 15;
    int row = cg * 16 + (l & 15);
    int col = ks * 32 + (l >> 4) * 8;
    const float4* src = reinterpret_cast<const float4*>(w + row * ENCH + col);
    float4 v0 = src[0], v1 = src[1];
    short8 r;
    r[0] = (short)f2bf_rne(v0.x); r[1] = (short)f2bf_rne(v0.y);
    r[2] = (short)f2bf_rne(v0.z); r[3] = (short)f2bf_rne(v0.w);
    r[4] = (short)f2bf_rne(v1.x); r[5] = (short)f2bf_rne(v1.y);
    r[6] = (short)f2bf_rne(v1.z); r[7] = (short)f2bf_rne(v1.w);
    *reinterpret_cast<short8*>(o + (size_t)idx * 8) = r;
  } else {
    __shared__ float dh[ENCH];
    int b = blockIdx.x - 32, tid = threadIdx.x;
    for (int i = tid; i < ENCH; i += 256) dh[i] = dec[b * ENCH + i];
    __syncthreads();
    if (tid < 128) {
      const float4* wr4 = reinterpret_cast<const float4*>(wdec + tid * ENCH);
      float acc = 0.f;
      for (int h4 = 0; h4 < ENCH / 4; ++h4) {
        float4 w4 = wr4[h4];
        acc += dh[h4 * 4 + 0] * w4.x + dh[h4 * 4 + 1] * w4.y +
               dh[h4 * 4 + 2] * w4.z + dh[h4 * 4 + 3] * w4.w;
      }
      dout[b * ATTN_ + tid] = acc;
    }
  }
}

// ---- K1: R13 + chunked load<->MFMA interleave. Strip loaded in 4 chunks
// of 4 ks (fp32 transients ta/tb = 32 VGPR); chunk q+1 issued while chunk q
// MFMAs (half-0), next segment's chunk 0 issued before half-1 -> loads in
// flight through the whole compute phase. Online cross-segment accumulation
// + block-end LDS reduce as R13.
__global__ __launch_bounds__(1024, 4) void k_main(
    const float* __restrict__ enc,            // [B,T,512] fp32
    const unsigned short* __restrict__ wfrag, // frag-linear bf16 W_enc
    const float* __restrict__ decproj,        // [B,128] fp32
    const float* __restrict__ vw,             // [128] fp32
    float* __restrict__ scores_raw,           // [B,T] raw scores
    float* __restrict__ ctx_part,             // [B*2][512]
    float* __restrict__ ml_part)              // [B*2][2]
{
  const int tid  = threadIdx.x;
  const int lane = tid & 63;
  const int wid  = tid >> 6;       // 16 waves
  const int l15  = lane & 15;
  const int g    = lane >> 4;

  __shared__ unsigned short w_lds[ATTN_ * ENCH];  // 128 KiB frag-linear
  __shared__ float dv_lds[ATTN_], vv_lds[ATTN_];

  const int b    = blockIdx.x >> 1;          // block-uniform batch
  const int seg0 = (blockIdx.x & 1) * 4;     // segment window within batch

#pragma unroll
  for (int r = 0; r < 8; ++r) {
    int i = r * 1024 + tid;
    reinterpret_cast<short8*>(w_lds)[i] = reinterpret_cast<const short8*>(wfrag)[i];
  }
  if (tid < 128)       dv_lds[tid] = decproj[b * ATTN_ + tid];
  else if (tid < 256)  vv_lds[tid - 128] = vw[tid - 128];
  __syncthreads();

  // ---- phase stagger: wave wid sleeps ~wid*384 cyc (one-time, inert) ----
#pragma unroll 1
  for (int k = 0; k < wid; ++k) __builtin_amdgcn_s_sleep(6);

  // wave-carried online state (h = l15*32 + g*8 + j for ctx8[j])
  float m_run = -INFINITY, l_run = 0.f;
  float ctx8[8];
#pragma unroll
  for (int j = 0; j < 8; ++j) ctx8[j] = 0.f;

  // per-wave base address (row = row0 + l15, cols g*8..)
  const float* arow = enc + ((size_t)b * T_SZ + seg0 * 256 + wid * 16 + l15) * ENCH + g * 8;

  // ---- prologue: issue chunk 0 of segment 0 ----
  float4 ta[4], tb[4];
#pragma unroll
  for (int j = 0; j < 4; ++j) {
    ta[j] = *reinterpret_cast<const float4*>(arow + j * 32);
    tb[j] = *reinterpret_cast<const float4*>(arow + j * 32 + 4);
  }

#pragma unroll 1
  for (int i = 0; i < SEGS_PER_BLK; ++i) {
    const int seg  = seg0 + i;
    const int row0 = seg * 256 + wid * 16;

    short8 af[16];
    float e[4] = {0.f, 0.f, 0.f, 0.f};

    // ---- half 0 (cg 0-3): chunked convert/issue/MFMA ----
    {
      f32x4 acc[4];
#pragma unroll
      for (int c = 0; c < 4; ++c) acc[c] = (f32x4){0.f, 0.f, 0.f, 0.f};
#pragma unroll
      for (int q = 0; q < 4; ++q) {
        // convert chunk q (waits its loads via register deps)
#pragma unroll
        for (int j = 0; j < 4; ++j) af[q * 4 + j] = pack8(ta[j], tb[j]);
        // issue chunk q+1 (WAR on ta/tb: cannot hoist above the converts)
        if (q < 3) {
#pragma unroll
          for (int j = 0; j < 4; ++j) {
            ta[j] = *reinterpret_cast<const float4*>(arow + (q * 4 + 4 + j) * 32);
            tb[j] = *reinterpret_cast<const float4*>(arow + (q * 4 + 4 + j) * 32 + 4);
          }
        }
        // MFMA chunk q, cg 0-3
#pragma unroll
        for (int j = 0; j < 4; ++j) {
          const int ks = q * 4 + j;
          const char* wb = (const char*)w_lds + ks * 1024 + lane * 16;
#pragma unroll
          for (int c = 0; c < 4; ++c) {
            short8 bf = *reinterpret_cast<const short8*>(wb + c * 16384);
            acc[c] = __builtin_amdgcn_mfma_f32_16x16x32_bf16(af[ks], bf, acc[c], 0, 0, 0);
          }
        }
      }
#pragma unroll
      for (int c = 0; c < 4; ++c) {
        int col = c * 16 + l15;
        float d = dv_lds[col], v = vv_lds[col];
#pragma unroll
        for (int r = 0; r < 4; ++r)
          e[r] += fast_tanh(acc[c][r] + d) * v;
      }
    }

    // ---- issue next segment's chunk 0 (covers half-1 + scores + ctx) ----
    if (i + 1 < SEGS_PER_BLK) {
      const float* anext = arow + 256 * ENCH;
#pragma unroll
      for (int j = 0; j < 4; ++j) {
        ta[j] = *reinterpret_cast<const float4*>(anext + j * 32);
        tb[j] = *reinterpret_cast<const float4*>(anext + j * 32 + 4);
      }
    }

    // ---- half 1 (cg 4-7): af complete, pure MFMA ----
    {
      f32x4 acc[4];
#pragma unroll
      for (int c = 0; c < 4; ++c) acc[c] = (f32x4){0.f, 0.f, 0.f, 0.f};
#pragma unroll
      for (int ks = 0; ks < 16; ++ks) {
        const char* wb = (const char*)w_lds + ks * 1024 + lane * 16 + 65536;
#pragma unroll
        for (int c = 0; c < 4; ++c) {
          short8 bf = *reinterpret_cast<const short8*>(wb + c * 16384);
          acc[c] = __builtin_amdgcn_mfma_f32_16x16x32_bf16(af[ks], bf, acc[c], 0, 0, 0);
        }
      }
#pragma unroll
      for (int c = 0; c < 4; ++c) {
        int col = (4 + c) * 16 + l15;
        float d = dv_lds[col], v = vv_lds[col];
#pragma unroll
        for (int r = 0; r < 4; ++r)
          e[r] += fast_tanh(acc[c][r] + d) * v;
      }
    }

    // ---- row scores via DPP; row = 4g+r ----
    float er[4];
#pragma unroll
    for (int r = 0; r < 4; ++r) er[r] = sum16(e[r]);
    if (l15 == 0) {
#pragma unroll
      for (int r = 0; r < 4; ++r)
        scores_raw[(size_t)b * T_SZ + row0 + g * 4 + r] = er[r];
    }

    // ---- wave softmax over this segment's 16 rows ----
    float mg = fmaxf(fmaxf(er[0], er[1]), fmaxf(er[2], er[3]));
    mg = fmaxf(mg, __shfl_xor(mg, 16));
    mg = fmaxf(mg, __shfl_xor(mg, 32));
    float x0 = __expf(er[0] - mg), x1 = __expf(er[1] - mg);
    float x2 = __expf(er[2] - mg), x3 = __expf(er[3] - mg);
    float xs = (x0 + x1) + (x2 + x3);
    xs += __shfl_xor(xs, 16);
    xs += __shfl_xor(xs, 32);
    float sel = (l15 & 3) == 0 ? er[0]
              : (l15 & 3) == 1 ? er[1]
              : (l15 & 3) == 2 ? er[2] : er[3];
    float smine = __shfl(sel, ((l15 >> 2) << 4) | (l15 & 3));
    const float p_me = __expf(smine - mg);   // p for row l15, rel. to mg

    // ---- segment ctx (rel. to mg) via DPP reduce from bf16 regs ----
    float cseg[8];
#pragma unroll
    for (int j = 0; j < 8; ++j) cseg[j] = 0.f;
#pragma unroll
    for (int ks = 0; ks < 16; ++ks) {
      float c[8];
#pragma unroll
      for (int jh = 0; jh < 4; ++jh) {
        c[jh * 2 + 0] = p_me * bfel(af[ks], jh, false);
        c[jh * 2 + 1] = p_me * bfel(af[ks], jh, true);
      }
#pragma unroll
      for (int j = 0; j < 8; ++j) c[j] = sum16(c[j]);
      if (l15 == ks) {
#pragma unroll
        for (int j = 0; j < 8; ++j) cseg[j] = c[j];
      }
    }

    // ---- online merge into wave-carried state ----
    float m_new  = fmaxf(m_run, mg);
    float scale  = __expf(m_run - m_new);   // 0 on first segment
    float fseg   = __expf(mg - m_new);
    l_run = l_run * scale + xs * fseg;
#pragma unroll
    for (int j = 0; j < 8; ++j) ctx8[j] = ctx8[j] * scale + cseg[j] * fseg;
    m_run = m_new;

    arow += 256 * ENCH;
  }

  // ---- block-end reduce of 16 wave-partials (reuse w_lds) ----
  __syncthreads();                          // all waves done with W
  float* cred = reinterpret_cast<float*>(w_lds);   // [16][512]
  float* cp = cred + wid * ENCH + l15 * 32 + g * 8;
#pragma unroll
  for (int j = 0; j < 8; ++j) cp[j] = ctx8[j];
  if (lane == 0) { dv_lds[wid * 2] = m_run; dv_lds[wid * 2 + 1] = l_run; }
  __syncthreads();

  if (tid < ENCH) {
    float M = dv_lds[0];
#pragma unroll
    for (int w = 1; w < 16; ++w) M = fmaxf(M, dv_lds[w * 2]);
    float L = 0.f, c = 0.f;
#pragma unroll
    for (int w = 0; w < 16; ++w) {
      float f = __expf(dv_lds[w * 2] - M);
      L += f * dv_lds[w * 2 + 1];
      c += f * cred[w * ENCH + tid];
    }
    const int widx2 = b * 2 + (blockIdx.x & 1);
    ctx_part[(size_t)widx2 * ENCH + tid] = c;
    if (tid == 0) {
      ml_part[widx2 * 2 + 0] = M;
      ml_part[widx2 * 2 + 1] = L;
    }
  }
}

// ---- K2: merge 2 partials per batch; normalize weights in place ----
__global__ void k_combine(const float* __restrict__ ctx_part,
                          const float* __restrict__ ml_part,
                          float* __restrict__ out_ctx,   // [B,512]
                          float* __restrict__ weights)   // [B,T], raw scores
{
  __shared__ float f0s, f1s, Msh, Lsh;
  int b = blockIdx.x, tid = threadIdx.x;   // 256 threads
  if (tid == 0) {
    float m0 = ml_part[b * 4 + 0], l0 = ml_part[b * 4 + 1];
    float m1 = ml_part[b * 4 + 2], l1 = ml_part[b * 4 + 3];
    float M  = fmaxf(m0, m1);
    float f0 = __expf(m0 - M), f1 = __expf(m1 - M);
    Msh = M; Lsh = f0 * l0 + f1 * l1; f0s = f0; f1s = f1;
  }
  __syncthreads();
  float M = Msh, Linv = 1.f / Lsh, f0 = f0s, f1 = f1s;
  for (int h = tid; h < ENCH; h += 256) {
    float a = f0 * ctx_part[(size_t)(b * 2) * ENCH + h] +
              f1 * ctx_part[(size_t)(b * 2 + 1) * ENCH + h];
    out_ctx[b * ENCH + h] = a * Linv;
  }
  for (int t = tid; t < T_SZ; t += 256) {
    float raw = weights[(size_t)b * T_SZ + t];
    weights[(size_t)b * T_SZ + t] = __expf(raw - M) * Linv;
  }
}

extern "C" void kernel_launch(void* const* d_in, const int* in_sizes, int n_in,
                              void* d_out, int out_size, void* d_ws, size_t ws_size,
                              hipStream_t stream) {
  const float* enc  = (const float*)d_in[0];
  const float* dec  = (const float*)d_in[1];
  const float* wenc = (const float*)d_in[2];
  const float* wdec = (const float*)d_in[3];
  const float* vw   = (const float*)d_in[4];

  float* out     = (float*)d_out;
  float* out_ctx = out;                       // [B,512]
  float* out_w   = out + B_SZ * ENCH;         // [B,T] raw scores -> weights

  char* ws = (char*)d_ws;
  unsigned short* wfrag = (unsigned short*)ws;                      // 131072 B
  float* decproj  = (float*)(ws + 131072);                          // 65536 B
  float* ml_part  = (float*)(ws + 131072 + 65536);                  // 2048 B
  float* ctx_part = (float*)(ws + 131072 + 65536 + 2048);           // 512 KiB

  hipLaunchKernelGGL(k_prep, dim3(160), dim3(256), 0, stream,
                     wenc, wfrag, dec, wdec, decproj);
  hipLaunchKernelGGL(k_main, dim3(NBLK), dim3(1024), 0, stream,
                     enc, wfrag, decproj, vw, out_w, ctx_part, ml_part);
  hipLaunchKernelGGL(k_combine, dim3(B_SZ), dim3(256), 0, stream,
                     ctx_part, ml_part, out_ctx, out_w);
}

// Round 15
// 148.060 us; speedup vs baseline: 1.1649x; 1.1649x over previous
//
#include <hip/hip_runtime.h>
#include <hip/hip_bf16.h>

#define B_SZ   128
#define T_SZ   2048
#define ENCH   512
#define ATTN_  128
#define NBLK   256               // persistent, 1 block/CU
#define SEGS_PER_BLK 4           // 4 x (16 waves x 16 rows) = 1024 rows/block

typedef __attribute__((ext_vector_type(8))) short short8;
typedef __attribute__((ext_vector_type(4))) float f32x4;

__device__ __forceinline__ unsigned short f2bf_rne(float f) {
  unsigned u = __builtin_bit_cast(unsigned, f);
  u += 0x7FFFu + ((u >> 16) & 1u);
  return (unsigned short)(u >> 16);
}
__device__ __forceinline__ float fast_tanh(float x) {
  float e = __expf(2.f * x);
  return 1.f - __fdividef(2.f, e + 1.f);
}
__device__ __forceinline__ short8 pack8(float4 a, float4 b) {
  union { unsigned u[4]; short8 s; } r;
  asm("v_cvt_pk_bf16_f32 %0, %1, %2" : "=v"(r.u[0]) : "v"(a.x), "v"(a.y));
  asm("v_cvt_pk_bf16_f32 %0, %1, %2" : "=v"(r.u[1]) : "v"(a.z), "v"(a.w));
  asm("v_cvt_pk_bf16_f32 %0, %1, %2" : "=v"(r.u[2]) : "v"(b.x), "v"(b.y));
  asm("v_cvt_pk_bf16_f32 %0, %1, %2" : "=v"(r.u[3]) : "v"(b.z), "v"(b.w));
  return r.s;
}
template<int CTRL>
__device__ __forceinline__ float dpp_add(float v) {
  int t = __builtin_amdgcn_update_dpp(0, __builtin_bit_cast(int, v),
                                      CTRL, 0xf, 0xf, true);
  return v + __builtin_bit_cast(float, t);
}
__device__ __forceinline__ float sum16(float v) {
  v = dpp_add<0xB1>(v);    // quad_perm xor1
  v = dpp_add<0x4E>(v);    // quad_perm xor2
  v = dpp_add<0x141>(v);   // row_half_mirror
  v = dpp_add<0x140>(v);   // row_mirror
  return v;
}
// bf16 element (packed in short8) -> f32
__device__ __forceinline__ float bfel(short8 v, int j_half, bool hi) {
  unsigned u = __builtin_bit_cast(unsigned, (int)((((int*)&v))[j_half]));
  return __builtin_bit_cast(float, hi ? (u & 0xFFFF0000u) : (u << 16));
}

// ---- K0 (fused prep): blocks 0-31 convert W_enc fp32->bf16 frag-linear;
//      blocks 32-159 compute dec_proj[b] = W_dec . dec[b]. ----
__global__ void k_prep(const float* __restrict__ w,
                       unsigned short* __restrict__ o,
                       const float* __restrict__ dec,
                       const float* __restrict__ wdec,
                       float* __restrict__ dout) {
  if (blockIdx.x < 32) {
    int idx = blockIdx.x * 256 + threadIdx.x;   // 8192 threads
    int l   = idx & 63;
    int wks = idx >> 6;
    int cg  = wks >> 4, ks = wks & 15;
    int row = cg * 16 + (l & 15);
    int col = ks * 32 + (l >> 4) * 8;
    const float4* src = reinterpret_cast<const float4*>(w + row * ENCH + col);
    float4 v0 = src[0], v1 = src[1];
    short8 r;
    r[0] = (short)f2bf_rne(v0.x); r[1] = (short)f2bf_rne(v0.y);
    r[2] = (short)f2bf_rne(v0.z); r[3] = (short)f2bf_rne(v0.w);
    r[4] = (short)f2bf_rne(v1.x); r[5] = (short)f2bf_rne(v1.y);
    r[6] = (short)f2bf_rne(v1.z); r[7] = (short)f2bf_rne(v1.w);
    *reinterpret_cast<short8*>(o + (size_t)idx * 8) = r;
  } else {
    __shared__ float dh[ENCH];
    int b = blockIdx.x - 32, tid = threadIdx.x;
    for (int i = tid; i < ENCH; i += 256) dh[i] = dec[b * ENCH + i];
    __syncthreads();
    if (tid < 128) {
      const float4* wr4 = reinterpret_cast<const float4*>(wdec + tid * ENCH);
      float acc = 0.f;
      for (int h4 = 0; h4 < ENCH / 4; ++h4) {
        float4 w4 = wr4[h4];
        acc += dh[h4 * 4 + 0] * w4.x + dh[h4 * 4 + 1] * w4.y +
               dh[h4 * 4 + 2] * w4.z + dh[h4 * 4 + 3] * w4.w;
      }
      dout[b * ATTN_ + tid] = acc;
    }
  }
}

// ---- K1: R12 structure + online cross-segment accumulation + block-end
// LDS reduce. Per-wave (m,l,ctx) carried across its 4 segments; block writes
// ONE partial (per 1024 rows) -> aux traffic 33MB -> 0.5MB.
__global__ __launch_bounds__(1024, 4) void k_main(
    const float* __restrict__ enc,            // [B,T,512] fp32
    const unsigned short* __restrict__ wfrag, // frag-linear bf16 W_enc
    const float* __restrict__ decproj,        // [B,128] fp32
    const float* __restrict__ vw,             // [128] fp32
    float* __restrict__ scores_raw,           // [B,T] raw scores
    float* __restrict__ ctx_part,             // [B*2][512]
    float* __restrict__ ml_part)              // [B*2][2]
{
  const int tid  = threadIdx.x;
  const int lane = tid & 63;
  const int wid  = tid >> 6;       // 16 waves
  const int l15  = lane & 15;
  const int g    = lane >> 4;

  __shared__ unsigned short w_lds[ATTN_ * ENCH];  // 128 KiB frag-linear
  __shared__ float dv_lds[ATTN_], vv_lds[ATTN_];

  const int b    = blockIdx.x >> 1;          // block-uniform batch
  const int seg0 = (blockIdx.x & 1) * 4;     // segment window within batch

#pragma unroll
  for (int r = 0; r < 8; ++r) {
    int i = r * 1024 + tid;
    reinterpret_cast<short8*>(w_lds)[i] = reinterpret_cast<const short8*>(wfrag)[i];
  }
  if (tid < 128)       dv_lds[tid] = decproj[b * ATTN_ + tid];
  else if (tid < 256)  vv_lds[tid - 128] = vw[tid - 128];
  __syncthreads();

  // ---- phase stagger: wave wid sleeps ~wid*384 cyc (one-time, inert) ----
#pragma unroll 1
  for (int k = 0; k < wid; ++k) __builtin_amdgcn_s_sleep(6);

  // wave-carried online state (h = l15*32 + g*8 + j for ctx8[j])
  float m_run = -INFINITY, l_run = 0.f;
  float ctx8[8];
#pragma unroll
  for (int j = 0; j < 8; ++j) ctx8[j] = 0.f;

#pragma unroll 1
  for (int i = 0; i < SEGS_PER_BLK; ++i) {
    const int seg  = seg0 + i;               // 0..7 within batch
    const int row0 = seg * 256 + wid * 16;
    const float* arow = enc + ((size_t)b * T_SZ + row0 + l15) * ENCH + g * 8;

    // ---- the ONLY enc read: strip -> bf16 regs (rolling convert) ----
    short8 af[16];
#pragma unroll
    for (int ks = 0; ks < 16; ++ks) {
      float4 a0 = *reinterpret_cast<const float4*>(arow + ks * 32);
      float4 a1 = *reinterpret_cast<const float4*>(arow + ks * 32 + 4);
      af[ks] = pack8(a0, a1);
    }

    // ---- two-pass MFMA + scores (acc[4] per pass) ----
    float e[4] = {0.f, 0.f, 0.f, 0.f};
#pragma unroll 1
    for (int half = 0; half < 2; ++half) {
      f32x4 acc[4];
#pragma unroll
      for (int c = 0; c < 4; ++c) acc[c] = (f32x4){0.f, 0.f, 0.f, 0.f};
#pragma unroll
      for (int ks = 0; ks < 16; ++ks) {
        const char* wb = (const char*)w_lds + ks * 1024 + lane * 16 + half * 65536;
#pragma unroll
        for (int c = 0; c < 4; ++c) {
          short8 bf = *reinterpret_cast<const short8*>(wb + c * 16384);
          acc[c] = __builtin_amdgcn_mfma_f32_16x16x32_bf16(af[ks], bf, acc[c], 0, 0, 0);
        }
      }
#pragma unroll
      for (int c = 0; c < 4; ++c) {
        int col = (half * 4 + c) * 16 + l15;
        float d = dv_lds[col], v = vv_lds[col];
#pragma unroll
        for (int r = 0; r < 4; ++r)
          e[r] += fast_tanh(acc[c][r] + d) * v;
      }
    }

    // ---- row scores via DPP; row = 4g+r ----
    float er[4];
#pragma unroll
    for (int r = 0; r < 4; ++r) er[r] = sum16(e[r]);
    if (l15 == 0) {
#pragma unroll
      for (int r = 0; r < 4; ++r)
        scores_raw[(size_t)b * T_SZ + row0 + g * 4 + r] = er[r];
    }

    // ---- wave softmax over this segment's 16 rows ----
    float mg = fmaxf(fmaxf(er[0], er[1]), fmaxf(er[2], er[3]));
    mg = fmaxf(mg, __shfl_xor(mg, 16));
    mg = fmaxf(mg, __shfl_xor(mg, 32));
    float x0 = __expf(er[0] - mg), x1 = __expf(er[1] - mg);
    float x2 = __expf(er[2] - mg), x3 = __expf(er[3] - mg);
    float xs = (x0 + x1) + (x2 + x3);
    xs += __shfl_xor(xs, 16);
    xs += __shfl_xor(xs, 32);
    float sel = (l15 & 3) == 0 ? er[0]
              : (l15 & 3) == 1 ? er[1]
              : (l15 & 3) == 2 ? er[2] : er[3];
    float smine = __shfl(sel, ((l15 >> 2) << 4) | (l15 & 3));
    const float p_me = __expf(smine - mg);   // p for row l15, rel. to mg

    // ---- segment ctx (rel. to mg) via DPP reduce from bf16 regs ----
    float cseg[8];
#pragma unroll
    for (int j = 0; j < 8; ++j) cseg[j] = 0.f;
#pragma unroll
    for (int ks = 0; ks < 16; ++ks) {
      float c[8];
#pragma unroll
      for (int jh = 0; jh < 4; ++jh) {
        c[jh * 2 + 0] = p_me * bfel(af[ks], jh, false);
        c[jh * 2 + 1] = p_me * bfel(af[ks], jh, true);
      }
#pragma unroll
      for (int j = 0; j < 8; ++j) c[j] = sum16(c[j]);
      if (l15 == ks) {
#pragma unroll
        for (int j = 0; j < 8; ++j) cseg[j] = c[j];
      }
    }

    // ---- online merge into wave-carried state ----
    float m_new  = fmaxf(m_run, mg);
    float scale  = __expf(m_run - m_new);   // 0 on first segment
    float fseg   = __expf(mg - m_new);
    l_run = l_run * scale + xs * fseg;
#pragma unroll
    for (int j = 0; j < 8; ++j) ctx8[j] = ctx8[j] * scale + cseg[j] * fseg;
    m_run = m_new;
  }

  // ---- block-end reduce of 16 wave-partials (reuse w_lds) ----
  __syncthreads();                          // all waves done with W
  float* cred = reinterpret_cast<float*>(w_lds);   // [16][512]
  float* cp = cred + wid * ENCH + l15 * 32 + g * 8;
#pragma unroll
  for (int j = 0; j < 8; ++j) cp[j] = ctx8[j];
  if (lane == 0) { dv_lds[wid * 2] = m_run; dv_lds[wid * 2 + 1] = l_run; }
  __syncthreads();

  if (tid < ENCH) {
    float M = dv_lds[0];
#pragma unroll
    for (int w = 1; w < 16; ++w) M = fmaxf(M, dv_lds[w * 2]);
    float L = 0.f, c = 0.f;
#pragma unroll
    for (int w = 0; w < 16; ++w) {
      float f = __expf(dv_lds[w * 2] - M);
      L += f * dv_lds[w * 2 + 1];
      c += f * cred[w * ENCH + tid];
    }
    const int widx2 = b * 2 + (blockIdx.x & 1);
    ctx_part[(size_t)widx2 * ENCH + tid] = c;
    if (tid == 0) {
      ml_part[widx2 * 2 + 0] = M;
      ml_part[widx2 * 2 + 1] = L;
    }
  }
}

// ---- K2: merge 2 partials per batch; normalize weights in place ----
__global__ void k_combine(const float* __restrict__ ctx_part,
                          const float* __restrict__ ml_part,
                          float* __restrict__ out_ctx,   // [B,512]
                          float* __restrict__ weights)   // [B,T], raw scores
{
  __shared__ float f0s, f1s, Msh, Lsh;
  int b = blockIdx.x, tid = threadIdx.x;   // 256 threads
  if (tid == 0) {
    float m0 = ml_part[b * 4 + 0], l0 = ml_part[b * 4 + 1];
    float m1 = ml_part[b * 4 + 2], l1 = ml_part[b * 4 + 3];
    float M  = fmaxf(m0, m1);
    float f0 = __expf(m0 - M), f1 = __expf(m1 - M);
    Msh = M; Lsh = f0 * l0 + f1 * l1; f0s = f0; f1s = f1;
  }
  __syncthreads();
  float M = Msh, Linv = 1.f / Lsh, f0 = f0s, f1 = f1s;
  for (int h = tid; h < ENCH; h += 256) {
    float a = f0 * ctx_part[(size_t)(b * 2) * ENCH + h] +
              f1 * ctx_part[(size_t)(b * 2 + 1) * ENCH + h];
    out_ctx[b * ENCH + h] = a * Linv;
  }
  for (int t = tid; t < T_SZ; t += 256) {
    float raw = weights[(size_t)b * T_SZ + t];
    weights[(size_t)b * T_SZ + t] = __expf(raw - M) * Linv;
  }
}

extern "C" void kernel_launch(void* const* d_in, const int* in_sizes, int n_in,
                              void* d_out, int out_size, void* d_ws, size_t ws_size,
                              hipStream_t stream) {
  const float* enc  = (const float*)d_in[0];
  const float* dec  = (const float*)d_in[1];
  const float* wenc = (const float*)d_in[2];
  const float* wdec = (const float*)d_in[3];
  const float* vw   = (const float*)d_in[4];

  float* out     = (float*)d_out;
  float* out_ctx = out;                       // [B,512]
  float* out_w   = out + B_SZ * ENCH;         // [B,T] raw scores -> weights

  char* ws = (char*)d_ws;
  unsigned short* wfrag = (unsigned short*)ws;                      // 131072 B
  float* decproj  = (float*)(ws + 131072);                          // 65536 B
  float* ml_part  = (float*)(ws + 131072 + 65536);                  // 2048 B
  float* ctx_part = (float*)(ws + 131072 + 65536 + 2048);           // 512 KiB

  hipLaunchKernelGGL(k_prep, dim3(160), dim3(256), 0, stream,
                     wenc, wfrag, dec, wdec, decproj);
  hipLaunchKernelGGL(k_main, dim3(NBLK), dim3(1024), 0, stream,
                     enc, wfrag, decproj, vw, out_w, ctx_part, ml_part);
  hipLaunchKernelGGL(k_combine, dim3(B_SZ), dim3(256), 0, stream,
                     ctx_part, ml_part, out_ctx, out_w);
}